// Round 18
// baseline (77.545 us; speedup 1.0000x reference)
//
#include <hip/hip_runtime.h>
#include <hip/hip_bf16.h>
#include <math.h>

// Problem dims
#define VOCAB 400000
#define D     300
#define L     2000
#define B     4
#define C1    64
#define C2    128
#define K2    500
#define HID   256
#define NCLS  5
#define NP1   1999   // pooled length after conv1+pool(300)
#define T2    1500   // conv2 out length
#define T2P   1536   // padded part row stride (bf16; 3072 B, 16B-aligned)
#define TPAD  2304   // padded t-length
#define S     8      // cin split groups (8 cin each)
#define CI    8      // cin per group
#define NK16  250    // MFMA K-steps (K=16 each): k = 2*k2 + h
#define BN    192    // t per block tile (32x32 shape: wave covers 96t)
#define SEGR  704    // staged B rows per block (reads need <= 690)
#define NWT   128    // weight-transpose blocks: 8 s * 16 cog(8 co each)
#define NC1B  (B * 500)  // conv1 blocks, 4 windows each

typedef __attribute__((ext_vector_type(8))) short short8v;
typedef __attribute__((ext_vector_type(16))) float f32x16;

__device__ __forceinline__ void gload_lds16(const void* g, void* l) {
    __builtin_amdgcn_global_load_lds(
        (const __attribute__((address_space(1))) void*)g,
        (__attribute__((address_space(3))) void*)l, 16, 0, 0);
}

// ---------------------------------------------------------------------------
// k_prep: fused [weight transpose (LDS-free)] + [embed+conv1+relu+pool].
// aT layout for 32x32x16: aT[s][k2][h][co128][e8] = w2[co][s*8+e][2*k2+h]
// (only the destination offset changed vs R17; source index identical).
// ---------------------------------------------------------------------------
__global__ __launch_bounds__(256) void k_prep(
    const int* __restrict__ x, const float* __restrict__ emb,
    const float* __restrict__ w1, const float* __restrict__ b1,
    const float* __restrict__ w2,
    __hip_bfloat16* __restrict__ in1T, __hip_bfloat16* __restrict__ aT)
{
    __shared__ float smem[1204];
    int bid = blockIdx.x, tid = threadIdx.x;
    if (bid < NWT) {
        // ---- weight transpose: s(8) x cog(16, 8 co each)
        int s = bid >> 4, cog = bid & 15;
        for (int u = tid; u < 4000; u += 256) {
            int co_l = u & 7, kg = u >> 3;       // kg = 2*k2+h, 0..499
            int k2 = kg >> 1, h = kg & 1;
            int co = cog * 8 + co_l;
            __hip_bfloat16 tmp[8];
#pragma unroll
            for (int e = 0; e < 8; ++e)
                tmp[e] = __float2bfloat16(
                    w2[((size_t)co * C1 + s * CI + e) * K2 + kg]);
            *reinterpret_cast<int4*>(
                aT + ((size_t)((s * NK16 + k2) * 2 + h)) * 1024 + (size_t)co * 8) =
                *reinterpret_cast<const int4*>(tmp);
        }
    } else {
        // ---- embed + conv1 + relu + maxpool(300), 4 windows per block
        int blk = bid - NWT;
        int b = blk / 500, pb = blk % 500;
        int p0 = pb * 4;
        float* sig = smem;           // 1204 floats: rows p0..p0+4 x 300 cols
        for (int i = tid; i < 301; i += 256) {   // strided: all 301 float4s
            int rj = i / 75, col = (i % 75) * 4;
            int xi = p0 + rj; if (xi > L - 1) xi = L - 1;     // clamp (guarded use)
            int row = x[b * L + xi];
            *reinterpret_cast<float4*>(sig + 4 * i) =
                *reinterpret_cast<const float4*>(emb + (size_t)row * D + col);
        }
        __syncthreads();
        int c = tid & 63, pg = tid >> 6;
        int p = p0 + pg;
        float wa = w1[c * 3 + 0], wb = w1[c * 3 + 1], wc = w1[c * 3 + 2];
        float bb = b1[c];
        int jb = 300 * pg;
        float m = -INFINITY;
        float4 cur = *reinterpret_cast<float4*>(sig + jb);   // broadcast reads
        for (int st = 0; st < 75; ++st) {
            float4 nxt = *reinterpret_cast<float4*>(sig + jb + 4 * st + 4);
            float xx[8] = {cur.x, cur.y, cur.z, cur.w, nxt.x, nxt.y, nxt.z, nxt.w};
#pragma unroll
            for (int q = 0; q < 4; ++q) {
                float v = fmaf(wc, xx[q + 2], fmaf(wb, xx[q + 1], fmaf(wa, xx[q], bb)));
                m = fmaxf(m, v);
            }
            cur = nxt;
        }
        if (p < NP1) {
            int sg = c >> 3, ci = c & 7;
            in1T[((size_t)(b * S + sg) * TPAD + p) * CI + ci] =
                __float2bfloat16(fmaxf(m, 0.0f));
        }
    }
}

// ---------------------------------------------------------------------------
// k2_mfma: conv2 bf16 GEMM on the 32x32x16 shape.
// Wave covers 32co x 96t (fa=1, fb=3) -> block 64co x 192t -> per-CU A-fetch
// HALVES (1 MB) and MFMA floor drops 24.3->20.2 us (2382 TF ceiling).
// grid 512 = 8s(bid&7=XCD) x 8ti x 4b x 2cog, 2 blocks/CU, no barriers in
// the 250-step K16 loop; A 4-deep named-register prefetch (covers L2 lat).
// Layouts: A[row=l&31][k=(l>>5)*8+e], B[k=(l>>5)*8+e][col=l&31] (analog of
// the refcheck'd 16x16 mapping); C/D col=l&31, row=(r&3)+8*(r>>2)+4*(l>>5).
// ---------------------------------------------------------------------------
__global__ __launch_bounds__(256, 2) void k2_mfma(
    const __hip_bfloat16* __restrict__ in1T,
    const __hip_bfloat16* __restrict__ aT,
    __hip_bfloat16* __restrict__ part)
{
    int bid = blockIdx.x;
    int s = bid & 7;                 // matches XCD round-robin
    int rem = bid >> 3;              // 0..63
    int ti = rem & 7;
    int b  = (rem >> 3) & 3;
    int cog = rem >> 5;              // 0..1
    int t0 = ti * BN;

    __shared__ __align__(16) __hip_bfloat16 seg[SEGR * CI];   // 11264 B

    int tid = threadIdx.x;
    int w = tid >> 6, l = tid & 63;
    int l32 = l & 31, h = l >> 5;
    int co0w = cog * 64 + (w & 1) * 32;   // wave's 32-co base within 128
    int tn0  = (w >> 1) * 96;             // wave's t base within 192

    // stage B once: 704 rows x 16 B, contiguous (in1T[b][s][t][ci])
    {
        const char* gsrc = (const char*)(in1T + ((size_t)(b * S + s) * TPAD + t0) * CI);
        char* lb = (char*)seg + w * 1024;
        gload_lds16(gsrc + (size_t)tid * 16, lb);                    // rows 0..255
        gload_lds16(gsrc + (size_t)(256 + tid) * 16, lb + 4096);     // 256..511
        if (tid < 192)                                               // 512..703
            gload_lds16(gsrc + (size_t)(512 + tid) * 16, lb + 8192);
    }
    __syncthreads();   // drains vmcnt(0): B fully in LDS; only barrier needed

    // per-lane A base: aT[s][k2][h][co128][e8]
    const __hip_bfloat16* abase =
        aT + (size_t)s * NK16 * 2048 + h * 1024 + (co0w + l32) * 8;

    f32x16 acc[3];
#pragma unroll
    for (int fb = 0; fb < 3; ++fb)
#pragma unroll
        for (int r = 0; r < 16; ++r) acc[fb][r] = 0.f;

#define LOADA(AR, KK)                                                         \
    AR = *reinterpret_cast<const short8v*>(abase + (size_t)(KK) * 2048);

#define STEP(AR, KK)                                                          \
    {                                                                         \
        short8v bfr[3];                                                       \
        _Pragma("unroll")                                                     \
        for (int fb = 0; fb < 3; ++fb)                                        \
            bfr[fb] = *reinterpret_cast<const short8v*>(                      \
                seg + (size_t)(tn0 + fb * 32 + l32 + 2 * (KK) + h) * 8);      \
        __builtin_amdgcn_s_setprio(1);                                        \
        _Pragma("unroll")                                                     \
        for (int fb = 0; fb < 3; ++fb)                                        \
            acc[fb] = __builtin_amdgcn_mfma_f32_32x32x16_bf16(                \
                AR, bfr[fb], acc[fb], 0, 0, 0);                               \
        __builtin_amdgcn_s_setprio(0);                                        \
    }

    short8v a0, a1, a2, a3;
    LOADA(a0, 0); LOADA(a1, 1); LOADA(a2, 2); LOADA(a3, 3);
    int k2 = 0;
#pragma unroll 1
    for (; k2 + 7 < NK16; k2 += 4) {     // k2 = 0,4,...,240; exits k2 = 244
        STEP(a0, k2);     LOADA(a0, k2 + 4);
        STEP(a1, k2 + 1); LOADA(a1, k2 + 5);
        STEP(a2, k2 + 2); LOADA(a2, k2 + 6);
        STEP(a3, k2 + 3); LOADA(a3, k2 + 7);
    }
    // k2 == 244: steps 244..249 remain; a0..a3 hold 244..247
    STEP(a0, 244); LOADA(a0, 248);
    STEP(a1, 245); LOADA(a1, 249);
    STEP(a2, 246);
    STEP(a3, 247);
    STEP(a0, 248);
    STEP(a1, 249);

#undef LOADA
#undef STEP

    // epilogue: C/D col = l&31 (t), row = (r&3)+8*(r>>2)+4*h (co within 32)
#pragma unroll
    for (int fb = 0; fb < 3; ++fb) {
        int t = t0 + tn0 + fb * 32 + l32;         // <= 1535 always
#pragma unroll
        for (int r = 0; r < 16; ++r) {
            int row = (r & 3) + 8 * (r >> 2) + 4 * h;
            float v = (t < T2) ? acc[fb][r] : -INFINITY;
            part[((size_t)(s * B + b) * C2 + co0w + row) * T2P + t] =
                __float2bfloat16(v);
        }
    }
}

// ---------------------------------------------------------------------------
// k2b: sum 8 bf16 partials (f32 accum) + bias, relu + maxpool -> h1[b][co].
// (R17-verified, unchanged)
// ---------------------------------------------------------------------------
__global__ __launch_bounds__(256) void k2b_pool(
    const __hip_bfloat16* __restrict__ part, const float* __restrict__ b2,
    float* __restrict__ h1)
{
    int bc = blockIdx.x;             // b*C2 + co
    int b = bc / C2, co = bc % C2;
    int tid = threadIdx.x;
    float m = -INFINITY;
    if (tid < 192) {
        int t8 = tid * 8;
        float sum[8] = {0.f, 0.f, 0.f, 0.f, 0.f, 0.f, 0.f, 0.f};
#pragma unroll
        for (int s = 0; s < S; ++s) {
            short8v v = *reinterpret_cast<const short8v*>(
                part + ((size_t)(s * B + b) * C2 + co) * T2P + t8);
#pragma unroll
            for (int e = 0; e < 8; ++e)
                sum[e] += __uint_as_float(((unsigned)(unsigned short)v[e]) << 16);
        }
#pragma unroll
        for (int e = 0; e < 8; ++e) m = fmaxf(m, sum[e]);
    }
    __shared__ float red[256];
    red[tid] = m;
    __syncthreads();
    for (int st = 128; st > 0; st >>= 1) {
        if (tid < st) red[tid] = fmaxf(red[tid], red[tid + st]);
        __syncthreads();
    }
    if (tid == 0) h1[bc] = fmaxf(red[0] + b2[co], 0.0f);
}

// ---------------------------------------------------------------------------
// k3: lin1 + relu + lin2 + softmax. One block per batch row. (unchanged)
// ---------------------------------------------------------------------------
__global__ __launch_bounds__(256) void k3_head(
    const float* __restrict__ h1,
    const float* __restrict__ wl1, const float* __restrict__ bl1,
    const float* __restrict__ wl2, const float* __restrict__ bl2,
    float* __restrict__ out)
{
    int b = blockIdx.x;
    int tid = threadIdx.x;
    __shared__ float xin[C2];
    __shared__ float hbuf[HID];
    __shared__ float lg[NCLS];
    if (tid < C2) xin[tid] = h1[b * C2 + tid];
    __syncthreads();
    float a = bl1[tid];
    for (int c = 0; c < C2; ++c) a = fmaf(xin[c], wl1[tid * C2 + c], a);
    hbuf[tid] = fmaxf(a, 0.0f);
    __syncthreads();
    if (tid < NCLS) {
        float lv = bl2[tid];
        for (int j = 0; j < HID; ++j) lv = fmaf(hbuf[j], wl2[tid * HID + j], lv);
        lg[tid] = lv;
    }
    __syncthreads();
    if (tid < NCLS) {
        float mx = lg[0];
        for (int i = 1; i < NCLS; ++i) mx = fmaxf(mx, lg[i]);
        float sum = 0.f;
        for (int i = 0; i < NCLS; ++i) sum += expf(lg[i] - mx);
        out[b * NCLS + tid] = expf(lg[tid] - mx) / sum;
    }
}

extern "C" void kernel_launch(void* const* d_in, const int* in_sizes, int n_in,
                              void* d_out, int out_size, void* d_ws, size_t ws_size,
                              hipStream_t stream)
{
    const int*   x   = (const int*)  d_in[0];
    const float* emb = (const float*)d_in[1];
    const float* w1  = (const float*)d_in[2];
    const float* b1  = (const float*)d_in[3];
    const float* w2  = (const float*)d_in[4];
    const float* b2  = (const float*)d_in[5];
    const float* wl1 = (const float*)d_in[6];
    const float* bl1 = (const float*)d_in[7];
    const float* wl2 = (const float*)d_in[8];
    const float* bl2 = (const float*)d_in[9];
    float* out = (float*)d_out;

    // workspace: part bf16 8*4*128*1536 (12.58 MB) | h1 512 f32 |
    // in1T 589824 bf16 | aT 8*250*2048 = 4,096,000 bf16
    __hip_bfloat16* part = (__hip_bfloat16*)d_ws;
    float* h1 = (float*)(part + (size_t)S * B * C2 * T2P);
    __hip_bfloat16* in1T = (__hip_bfloat16*)(h1 + 512);
    __hip_bfloat16* aT   = in1T + (size_t)B * S * TPAD * CI;

    hipLaunchKernelGGL(k_prep, dim3(NWT + NC1B), dim3(256), 0, stream,
                       x, emb, w1, b1, w2, in1T, aT);
    hipLaunchKernelGGL(k2_mfma, dim3(512), dim3(256), 0, stream, in1T, aT, part);
    hipLaunchKernelGGL(k2b_pool, dim3(B * C2), dim3(256), 0, stream, part, b2, h1);
    hipLaunchKernelGGL(k3_head, dim3(B), dim3(256), 0, stream,
                       h1, wl1, bl1, wl2, bl2, out);
}

// Round 19
// 74.491 us; speedup vs baseline: 1.0410x; 1.0410x over previous
//
#include <hip/hip_runtime.h>
#include <hip/hip_bf16.h>
#include <math.h>

// Problem dims
#define VOCAB 400000
#define D     300
#define L     2000
#define B     4
#define C1    64
#define C2    128
#define K2    500
#define HID   256
#define NCLS  5
#define NP1   1999   // pooled length after conv1+pool(300)
#define T2    1500   // conv2 out length
#define T2P   1536   // padded part row stride (bf16; 3072 B, 16B-aligned)
#define TPAD  2304   // padded t-length (staging reads up to t0max+639 = 2079)
#define S     8      // cin split groups (8 cin each)
#define CI    8      // cin per group
#define NK2   125    // MFMA K-steps: k = 4*k2 + g, K=32 per step
#define BN    96     // t per block tile
#define SEGR  640    // staged B rows per block (reads need <= 594)
#define NWT   128    // weight-transpose blocks: 8 s * 16 cog(8 co each)
#define NC1B  (B * 500)  // conv1 blocks, 4 windows each

typedef __attribute__((ext_vector_type(8))) short short8v;
typedef __attribute__((ext_vector_type(4))) float f32x4;

__device__ __forceinline__ void gload_lds16(const void* g, void* l) {
    __builtin_amdgcn_global_load_lds(
        (const __attribute__((address_space(1))) void*)g,
        (__attribute__((address_space(3))) void*)l, 16, 0, 0);
}

// ---------------------------------------------------------------------------
// k_prep: fused [weight transpose (LDS-free)] + [embed+conv1+relu+pool].
// (R14-verified, strided 301-float4 staging.)
// ---------------------------------------------------------------------------
__global__ __launch_bounds__(256) void k_prep(
    const int* __restrict__ x, const float* __restrict__ emb,
    const float* __restrict__ w1, const float* __restrict__ b1,
    const float* __restrict__ w2,
    __hip_bfloat16* __restrict__ in1T, __hip_bfloat16* __restrict__ aT)
{
    __shared__ float smem[1204];
    int bid = blockIdx.x, tid = threadIdx.x;
    if (bid < NWT) {
        // ---- weight transpose: s(8) x cog(16, 8 co each)
        int s = bid >> 4, cog = bid & 15;
        for (int u = tid; u < 4000; u += 256) {
            int co_l = u & 7, kg = u >> 3;       // kg = k2*4+g, 0..499
            int k2 = kg >> 2, g = kg & 3;
            int co = cog * 8 + co_l;
            __hip_bfloat16 tmp[8];
#pragma unroll
            for (int e = 0; e < 8; ++e)
                tmp[e] = __float2bfloat16(
                    w2[((size_t)co * C1 + s * CI + e) * K2 + 4 * k2 + g]);
            *reinterpret_cast<int4*>(
                aT + ((size_t)((s * NK2 + k2) * 4 + g)) * 1024 + (size_t)co * 8) =
                *reinterpret_cast<const int4*>(tmp);
        }
    } else {
        // ---- embed + conv1 + relu + maxpool(300), 4 windows per block
        int blk = bid - NWT;
        int b = blk / 500, pb = blk % 500;
        int p0 = pb * 4;
        float* sig = smem;           // 1204 floats: rows p0..p0+4 x 300 cols
        for (int i = tid; i < 301; i += 256) {   // strided: all 301 float4s
            int rj = i / 75, col = (i % 75) * 4;
            int xi = p0 + rj; if (xi > L - 1) xi = L - 1;     // clamp (guarded use)
            int row = x[b * L + xi];
            *reinterpret_cast<float4*>(sig + 4 * i) =
                *reinterpret_cast<const float4*>(emb + (size_t)row * D + col);
        }
        __syncthreads();
        int c = tid & 63, pg = tid >> 6;
        int p = p0 + pg;
        float wa = w1[c * 3 + 0], wb = w1[c * 3 + 1], wc = w1[c * 3 + 2];
        float bb = b1[c];
        int jb = 300 * pg;
        float m = -INFINITY;
        float4 cur = *reinterpret_cast<float4*>(sig + jb);   // broadcast reads
        for (int st = 0; st < 75; ++st) {
            float4 nxt = *reinterpret_cast<float4*>(sig + jb + 4 * st + 4);
            float xx[8] = {cur.x, cur.y, cur.z, cur.w, nxt.x, nxt.y, nxt.z, nxt.w};
#pragma unroll
            for (int q = 0; q < 4; ++q) {
                float v = fmaf(wc, xx[q + 2], fmaf(wb, xx[q + 1], fmaf(wa, xx[q], bb)));
                m = fmaxf(m, v);
            }
            cur = nxt;
        }
        if (p < NP1) {
            int sg = c >> 3, ci = c & 7;
            in1T[((size_t)(b * S + sg) * TPAD + p) * CI + ci] =
                __float2bfloat16(fmaxf(m, 0.0f));
        }
    }
}

// ---------------------------------------------------------------------------
// k2_mfma: conv2 as bf16 MFMA GEMM, cin split 8 ways. (R17-verified optimum:
// 16x16x32 shape, fa=4/fb=3, 2 phase-diverse blocks/CU, no barriers in loop,
// A 2-deep register prefetch from L2, bf16 partials with -inf padding.)
// ---------------------------------------------------------------------------
__global__ __launch_bounds__(256, 2) void k2_mfma(
    const __hip_bfloat16* __restrict__ in1T,
    const __hip_bfloat16* __restrict__ aT,
    __hip_bfloat16* __restrict__ part)
{
    int bid = blockIdx.x;
    int s = bid & 7;                 // matches XCD round-robin
    int rem = bid >> 3;              // 0..63
    int b = rem >> 4, ti = rem & 15;
    int t0 = ti * BN;

    __shared__ __align__(16) __hip_bfloat16 seg[SEGR * CI];   // 10240 B

    int tid = threadIdx.x;
    int w = tid >> 6, l = tid & 63;
    int lane16 = l & 15, g = l >> 4;
    int co0w = (w & 1) * 64;         // 2 co-halves
    int tn0  = (w >> 1) * 48;        // 2 t-halves

    // stage B once: 640 rows x 16 B, contiguous (in1T[b][s][t][ci])
    {
        const char* gsrc = (const char*)(in1T + ((size_t)(b * S + s) * TPAD + t0) * CI);
        char* lb = (char*)seg + w * 1024;
        gload_lds16(gsrc + (size_t)tid * 16, lb);                    // rows 0..255
        gload_lds16(gsrc + (size_t)(256 + tid) * 16, lb + 4096);     // 256..511
        if (tid < 128)                                               // waves 0,1 full
            gload_lds16(gsrc + (size_t)(512 + tid) * 16, lb + 8192); // 512..639
    }
    __syncthreads();   // drains vmcnt(0): B fully in LDS; only barrier needed

    // per-lane A base: aT[s][k2][g][co][e], frag fa covers co0w+fa*16..+15
    const __hip_bfloat16* abase =
        aT + (size_t)s * NK2 * 4096 + g * 1024 + (co0w + lane16) * 8;

    f32x4 acc[4][3];
#pragma unroll
    for (int fa = 0; fa < 4; ++fa)
#pragma unroll
        for (int fb = 0; fb < 3; ++fb) acc[fa][fb] = (f32x4){0.f, 0.f, 0.f, 0.f};

#define LOADA(AR, KK)                                                         \
    {                                                                         \
        _Pragma("unroll")                                                     \
        for (int fa = 0; fa < 4; ++fa)                                        \
            AR[fa] = *reinterpret_cast<const short8v*>(                       \
                abase + (size_t)(KK) * 4096 + fa * 128);                      \
    }

#define STEP(AR, KK)                                                         \
    {                                                                         \
        short8v bfr[3];                                                       \
        _Pragma("unroll")                                                     \
        for (int fb = 0; fb < 3; ++fb)                                        \
            bfr[fb] = *reinterpret_cast<const short8v*>(                      \
                seg + (size_t)(tn0 + fb * 16 + lane16 + 4 * (KK) + g) * 8);   \
        __builtin_amdgcn_s_setprio(1);                                        \
        _Pragma("unroll")                                                     \
        for (int fa = 0; fa < 4; ++fa) {                                      \
            _Pragma("unroll")                                                 \
            for (int fb = 0; fb < 3; ++fb)                                    \
                acc[fa][fb] = __builtin_amdgcn_mfma_f32_16x16x32_bf16(        \
                    AR[fa], bfr[fb], acc[fa][fb], 0, 0, 0);                   \
        }                                                                     \
        __builtin_amdgcn_s_setprio(0);                                        \
    }

    short8v a0[4], a1[4];
    LOADA(a0, 0);
    LOADA(a1, 1);
    int k2 = 0;
#pragma unroll 1
    for (; k2 + 3 < NK2; k2 += 2) {      // k2 = 0,2,...,120; exits k2 = 122
        STEP(a0, k2);
        LOADA(a0, k2 + 2);
        STEP(a1, k2 + 1);
        LOADA(a1, k2 + 3);
    }
    STEP(a0, k2);          // 122
    LOADA(a0, k2 + 2);
    STEP(a1, k2 + 1);      // 123
    STEP(a0, k2 + 2);      // 124

#undef LOADA
#undef STEP

    // epilogue: C/D layout col=lane16 (t), row=4*g+r (co within 16).
    // bf16 store; t >= T2 lanes write -inf (padding consumed by k2b's max).
#pragma unroll
    for (int fa = 0; fa < 4; ++fa) {
#pragma unroll
        for (int fb = 0; fb < 3; ++fb) {
            int t = t0 + tn0 + fb * 16 + lane16;      // <= 1535 always
            int cob = co0w + fa * 16 + 4 * g;
#pragma unroll
            for (int r = 0; r < 4; ++r) {
                float v = (t < T2) ? acc[fa][fb][r] : -INFINITY;
                part[((size_t)(s * B + b) * C2 + cob + r) * T2P + t] =
                    __float2bfloat16(v);
            }
        }
    }
}

// ---------------------------------------------------------------------------
// k2b: sum 8 bf16 partials (f32 accum) + bias, relu + maxpool -> h1[b][co].
// ---------------------------------------------------------------------------
__global__ __launch_bounds__(256) void k2b_pool(
    const __hip_bfloat16* __restrict__ part, const float* __restrict__ b2,
    float* __restrict__ h1)
{
    int bc = blockIdx.x;             // b*C2 + co
    int b = bc / C2, co = bc % C2;
    int tid = threadIdx.x;
    float m = -INFINITY;
    if (tid < 192) {
        int t8 = tid * 8;
        float sum[8] = {0.f, 0.f, 0.f, 0.f, 0.f, 0.f, 0.f, 0.f};
#pragma unroll
        for (int s = 0; s < S; ++s) {
            short8v v = *reinterpret_cast<const short8v*>(
                part + ((size_t)(s * B + b) * C2 + co) * T2P + t8);
#pragma unroll
            for (int e = 0; e < 8; ++e)
                sum[e] += __uint_as_float(((unsigned)(unsigned short)v[e]) << 16);
        }
#pragma unroll
        for (int e = 0; e < 8; ++e) m = fmaxf(m, sum[e]);
    }
    __shared__ float red[256];
    red[tid] = m;
    __syncthreads();
    for (int st = 128; st > 0; st >>= 1) {
        if (tid < st) red[tid] = fmaxf(red[tid], red[tid + st]);
        __syncthreads();
    }
    if (tid == 0) h1[bc] = fmaxf(red[0] + b2[co], 0.0f);
}

// ---------------------------------------------------------------------------
// k3: lin1 + relu + lin2 + softmax. One block per batch row.
// ---------------------------------------------------------------------------
__global__ __launch_bounds__(256) void k3_head(
    const float* __restrict__ h1,
    const float* __restrict__ wl1, const float* __restrict__ bl1,
    const float* __restrict__ wl2, const float* __restrict__ bl2,
    float* __restrict__ out)
{
    int b = blockIdx.x;
    int tid = threadIdx.x;
    __shared__ float xin[C2];
    __shared__ float hbuf[HID];
    __shared__ float lg[NCLS];
    if (tid < C2) xin[tid] = h1[b * C2 + tid];
    __syncthreads();
    float a = bl1[tid];
    for (int c = 0; c < C2; ++c) a = fmaf(xin[c], wl1[tid * C2 + c], a);
    hbuf[tid] = fmaxf(a, 0.0f);
    __syncthreads();
    if (tid < NCLS) {
        float lv = bl2[tid];
        for (int j = 0; j < HID; ++j) lv = fmaf(hbuf[j], wl2[tid * HID + j], lv);
        lg[tid] = lv;
    }
    __syncthreads();
    if (tid < NCLS) {
        float mx = lg[0];
        for (int i = 1; i < NCLS; ++i) mx = fmaxf(mx, lg[i]);
        float sum = 0.f;
        for (int i = 0; i < NCLS; ++i) sum += expf(lg[i] - mx);
        out[b * NCLS + tid] = expf(lg[tid] - mx) / sum;
    }
}

extern "C" void kernel_launch(void* const* d_in, const int* in_sizes, int n_in,
                              void* d_out, int out_size, void* d_ws, size_t ws_size,
                              hipStream_t stream)
{
    const int*   x   = (const int*)  d_in[0];
    const float* emb = (const float*)d_in[1];
    const float* w1  = (const float*)d_in[2];
    const float* b1  = (const float*)d_in[3];
    const float* w2  = (const float*)d_in[4];
    const float* b2  = (const float*)d_in[5];
    const float* wl1 = (const float*)d_in[6];
    const float* bl1 = (const float*)d_in[7];
    const float* wl2 = (const float*)d_in[8];
    const float* bl2 = (const float*)d_in[9];
    float* out = (float*)d_out;

    // workspace: part bf16 8*4*128*1536 = 6,291,456 elems (12.58 MB) |
    // h1 512 f32 | in1T 589824 bf16 | aT 4,096,000 bf16
    __hip_bfloat16* part = (__hip_bfloat16*)d_ws;
    float* h1 = (float*)(part + (size_t)S * B * C2 * T2P);
    __hip_bfloat16* in1T = (__hip_bfloat16*)(h1 + 512);
    __hip_bfloat16* aT   = in1T + (size_t)B * S * TPAD * CI;

    hipLaunchKernelGGL(k_prep, dim3(NWT + NC1B), dim3(256), 0, stream,
                       x, emb, w1, b1, w2, in1T, aT);
    hipLaunchKernelGGL(k2_mfma, dim3(512), dim3(256), 0, stream, in1T, aT, part);
    hipLaunchKernelGGL(k2b_pool, dim3(B * C2), dim3(256), 0, stream, part, b2, h1);
    hipLaunchKernelGGL(k3_head, dim3(B), dim3(256), 0, stream,
                       h1, wl1, bl1, wl2, bl2, out);
}